// Round 11
// baseline (688.580 us; speedup 1.0000x reference)
//
#include <hip/hip_runtime.h>

#define B_ 8
#define S_ 4096
#define IN_ 64
#define HID_ 512
#define NSTEP 12
#define SP_ (S_ + 2)
#define NP_ (B_ * SP_)
#define NTOT (B_ * S_)

typedef unsigned short u16;
typedef __attribute__((ext_vector_type(8))) short bf16x8;
typedef __attribute__((ext_vector_type(4))) float f32x4;
typedef __attribute__((ext_vector_type(16))) float f32x16;

__device__ __forceinline__ u16 f2bf(float f) {
  unsigned u = __float_as_uint(f);
  u += 0x7fffu + ((u >> 16) & 1u);
  return (u16)(u >> 16);
}

__device__ __forceinline__ void gload16(const void* g, void* l) {
  __builtin_amdgcn_global_load_lds((const __attribute__((address_space(1))) void*)g,
                                   (__attribute__((address_space(3))) void*)l, 16, 0, 0);
}

// ---------------- setup: bf16 conversions + weight transposes + pad-row zeroing ----------------
__global__ void setup_kernel(const float* __restrict__ x, const float* __restrict__ Wc,
                             const float* __restrict__ Wi, const float* __restrict__ Wo,
                             u16* __restrict__ wcb, u16* __restrict__ wib,
                             u16* __restrict__ wob, u16* __restrict__ xbf,
                             u16* __restrict__ h0, u16* __restrict__ h1) {
  const int n_wc = 3 * HID_ * HID_;       // wcb[k][o][i] = Wc[o][i][k]
  const int n_wio = IN_ * HID_;
  const int n_xb = NTOT * IN_;
  const int n_pad = 2 * B_ * 2 * HID_;
  const long total = (long)n_wc + 2 * n_wio + n_xb + n_pad;
  for (long u = (long)blockIdx.x * blockDim.x + threadIdx.x; u < total;
       u += (long)gridDim.x * blockDim.x) {
    long v = u;
    if (v < n_wc) {
      int k = (int)(v / (HID_ * HID_));
      int rem = (int)(v % (HID_ * HID_));
      int o = rem / HID_, i = rem % HID_;
      wcb[v] = f2bf(Wc[((long)o * HID_ + i) * 3 + k]);
    } else if ((v -= n_wc) < n_wio) {      // wib[i][j] = Wi[j][i]
      int i = (int)(v / IN_), j = (int)(v % IN_);
      wib[v] = f2bf(Wi[j * HID_ + i]);
    } else if ((v -= n_wio) < n_wio) {     // wob[j][i] = Wo[i][j]
      int j = (int)(v / HID_), i = (int)(v % HID_);
      wob[v] = f2bf(Wo[i * IN_ + j]);
    } else if ((v -= n_wio) < n_xb) {
      xbf[v] = f2bf(x[v]);
    } else {
      v -= n_xb;                           // zero pad rows (s=-1 and s=S per batch, both buffers)
      int buf = (int)(v / (B_ * 2 * HID_));
      int r = (int)(v % (B_ * 2 * HID_));
      int b = r / (2 * HID_);
      int q = r % (2 * HID_);
      int side = q / HID_, i = q % HID_;
      long p = (long)b * SP_ + (side ? (S_ + 1) : 0);
      (buf ? h1 : h0)[p * HID_ + i] = 0;
    }
  }
}

// ---------------- proj_in: h0[n][i] = x[n][:] @ W_in[:,i] + b_in  (bf16 MFMA, K=64) ----------------
__global__ __launch_bounds__(256, 2) void proj_in_gemm(const u16* __restrict__ xb,
                                                       const u16* __restrict__ wib,
                                                       const float* __restrict__ bin,
                                                       u16* __restrict__ hout) {
  __shared__ __align__(16) u16 Ab[128 * 64];
  __shared__ __align__(16) u16 Bb[128 * 64];
  const int tid = threadIdx.x, wid = tid >> 6, lane = tid & 63;
  const int nt = blockIdx.x, mt = blockIdx.y;
  const int wr = wid >> 1, wcn = wid & 1, fr = lane & 15, fq = lane >> 4;
#pragma unroll
  for (int c = 0; c < 4; ++c) {
    const int ch = wid * 4 + c;
    const int row = ch * 8 + (lane >> 3), cb = (lane & 7) * 8;
    gload16(wib + (mt * 128 + row) * 64 + cb, &Ab[ch * 512]);
    gload16(xb + ((long)nt * 128 + row) * 64 + cb, &Bb[ch * 512]);
  }
  f32x4 acc[4][4];
#pragma unroll
  for (int m = 0; m < 4; ++m)
#pragma unroll
    for (int n = 0; n < 4; ++n) acc[m][n] = {0.f, 0.f, 0.f, 0.f};
  __syncthreads();
#pragma unroll
  for (int t = 0; t < 2; ++t) {
    const int j0 = t * 32;
    bf16x8 af[4], bfv[4];
#pragma unroll
    for (int m = 0; m < 4; ++m)
      af[m] = *(const bf16x8*)&Ab[(wr * 64 + m * 16 + fr) * 64 + j0 + fq * 8];
#pragma unroll
    for (int n = 0; n < 4; ++n)
      bfv[n] = *(const bf16x8*)&Bb[(wcn * 64 + n * 16 + fr) * 64 + j0 + fq * 8];
#pragma unroll
    for (int m = 0; m < 4; ++m)
#pragma unroll
      for (int n = 0; n < 4; ++n)
        acc[m][n] = __builtin_amdgcn_mfma_f32_16x16x32_bf16(af[m], bfv[n], acc[m][n], 0, 0, 0);
  }
  const int n0 = nt * 128;
  const int bb = n0 / S_, s0v = n0 % S_;
  const int prow = bb * SP_ + s0v + 1;
#pragma unroll
  for (int m = 0; m < 4; ++m) {
    const int i = mt * 128 + wr * 64 + m * 16 + fq * 4;
    const float4 bias = *(const float4*)&bin[i];
#pragma unroll
    for (int n = 0; n < 4; ++n) {
      const int nl = wcn * 64 + n * 16 + fr;
      const long p = prow + nl;
      union { u16 q[4]; uint2 v; } u;
      u.q[0] = f2bf(acc[m][n][0] + bias.x);
      u.q[1] = f2bf(acc[m][n][1] + bias.y);
      u.q[2] = f2bf(acc[m][n][2] + bias.z);
      u.q[3] = f2bf(acc[m][n][3] + bias.w);
      *(uint2*)&hout[p * HID_ + i] = u.v;
    }
  }
}

// ---------------- conv step: R3 skeleton + 32x32x16 MFMA + XCD swizzle ----------------
// C[o,n] = relu(sum_{k,i} W[o,i,k] h[i,n+k-1] + b), bf16 in/out.
// 256x256 tile, BK=32, 8 waves x (128x64 C as 4mf x 2nf of 32x32), 4 LDS bufs x 32KB,
// depth-3 gload prefetch, single barrier + vmcnt(8) gate per tile (R3-proven).
// 32x32x16 halves MFMA count (16/wave/tile @8.07cy: per-CU 1033 vs 1242 cy) at the
// same 12 ds_read_b128/wave/tile. A/B/C/D lane maps HW-verified in R5+R6.
// XCD swizzle: bid -> swz=(bid&7)*32+(bid>>3); XCD c owns 32 blocks sharing one
// 256-row weight panel (mt) + contiguous n-range -> A re-reads are XCD-L2-hits.
__global__ __launch_bounds__(512, 2) void conv_gemm11(const u16* __restrict__ hin,
                                                      u16* __restrict__ hout,
                                                      const u16* __restrict__ wcb,
                                                      const float* __restrict__ bconv) {
  extern __shared__ __align__(16) u16 smem[];
  const int tid = threadIdx.x;
  const int w = tid >> 6, lane = tid & 63;
  const int wm = w >> 2, wn = w & 3;          // 2 x 4 wave grid; per-wave C = 128 x 64
  const int r32 = lane & 31, khi = lane >> 5;
  const int bid = blockIdx.x;
  const int swzid = (bid & 7) * 32 + (bid >> 3);   // bijective (256 = 8*32)
  const int mt = swzid >> 7, nt = swzid & 127;
  const int mbase = mt * 256;
  const int n0 = nt * 256;
  const int bb = n0 / S_, s0 = n0 % S_;
  const int prow0 = bb * SP_ + s0;            // tap-k B rows start at prow0+k

  // staging (R3-verified): linear LDS byte d = tid*16 within an 8KB strip;
  // logical byte = d ^ ((d>>7)&3)<<4 -> pre-swizzled global source.
  const int tl = (tid * 16) ^ (((tid >> 3) & 3) << 4);
  const int srow = tl >> 6;                   // 0..127
  const int scol = (tl & 63) >> 1;            // element col (multiple of 8)
  const int wdst = w * 1024;

  auto stage = [&](int u) {
    if (u > 47) u = 47;                       // tail clamp keeps vmcnt accounting uniform
    const int kk = u % 3;                     // tap-inner: B re-reads L2-hot
    const int i0 = (u / 3) * 32;
    char* base = (char*)smem + (u & 3) * 32768;
    const u16* ga = wcb + (size_t)kk * (HID_ * HID_) + (size_t)(mbase + srow) * HID_ + i0 + scol;
    const u16* gb = hin + (size_t)(prow0 + kk + srow) * HID_ + i0 + scol;
    gload16(ga, base + wdst);
    gload16(ga + 128 * HID_, base + 8192 + wdst);
    gload16(gb, base + 16384 + wdst);
    gload16(gb + 128 * HID_, base + 24576 + wdst);
  };

  f32x16 acc[4][2];
#pragma unroll
  for (int mf = 0; mf < 4; ++mf)
#pragma unroll
    for (int nf = 0; nf < 2; ++nf)
#pragma unroll
      for (int e = 0; e < 16; ++e) acc[mf][nf][e] = 0.f;

  // ds_read constants (R5-verified): row byte = row*64, col = ks*32 + khi*16,
  // physical col = col ^ g with g = ((r32>>1)&3)<<4 (row low 5 bits = r32 for all frags).
  const int g = ((r32 >> 1) & 3) << 4;
  const int c0 = ((khi * 16) ^ (g & 16)) + (g & 32);        // ks = 0
  const int c1 = ((khi * 16) ^ (g & 16)) + (32 ^ (g & 32)); // ks = 1
  const int abase = (wm * 128 + r32) * 64;    // + mf*2048
  const int bbase = (wn * 64 + r32) * 64;     // + nf*2048, within B half (16KB offset)

  stage(0); stage(1); stage(2);               // depth-3 prologue (12 loads outstanding)

#pragma unroll 12
  for (int t = 0; t < 48; ++t) {
    const char* A = (const char*)smem + (t & 3) * 32768;
    const char* Bv = A + 16384;

    // this wave's tile-t loads done (<=8 outstanding); barrier proves all waves'
    asm volatile("s_waitcnt vmcnt(8)" ::: "memory");
    __builtin_amdgcn_sched_barrier(0);
    __builtin_amdgcn_s_barrier();
    __builtin_amdgcn_sched_barrier(0);

    bf16x8 a0[4], a1[4], bv0[2], bv1[2];
    // group 1: A ks0 (4) + B ks0+ks1 (4)
#pragma unroll
    for (int mf = 0; mf < 4; ++mf)
      a0[mf] = *(const bf16x8*)(A + abase + mf * 2048 + c0);
#pragma unroll
    for (int nf = 0; nf < 2; ++nf) {
      bv0[nf] = *(const bf16x8*)(Bv + bbase + nf * 2048 + c0);
      bv1[nf] = *(const bf16x8*)(Bv + bbase + nf * 2048 + c1);
    }
    __builtin_amdgcn_sched_barrier(0);
    // prefetch K-tile t+3
    stage(t + 3);
    __builtin_amdgcn_sched_barrier(0);
    // group 2: A ks1 (4)
#pragma unroll
    for (int mf = 0; mf < 4; ++mf)
      a1[mf] = *(const bf16x8*)(A + abase + mf * 2048 + c1);
    __builtin_amdgcn_sched_barrier(0);

    // phase 0: ks0 frags ready (group 2 may still fly)
    asm volatile("s_waitcnt lgkmcnt(4)" ::: "memory");
    __builtin_amdgcn_sched_barrier(0);
    __builtin_amdgcn_s_setprio(1);
#pragma unroll
    for (int mf = 0; mf < 4; ++mf)
#pragma unroll
      for (int nf = 0; nf < 2; ++nf)
        acc[mf][nf] = __builtin_amdgcn_mfma_f32_32x32x16_bf16(a0[mf], bv0[nf], acc[mf][nf], 0, 0, 0);
    __builtin_amdgcn_s_setprio(0);
    __builtin_amdgcn_sched_barrier(0);

    // phase 1: ks1
    asm volatile("s_waitcnt lgkmcnt(0)" ::: "memory");
    __builtin_amdgcn_sched_barrier(0);
    __builtin_amdgcn_s_setprio(1);
#pragma unroll
    for (int mf = 0; mf < 4; ++mf)
#pragma unroll
      for (int nf = 0; nf < 2; ++nf)
        acc[mf][nf] = __builtin_amdgcn_mfma_f32_32x32x16_bf16(a1[mf], bv1[nf], acc[mf][nf], 0, 0, 0);
    __builtin_amdgcn_s_setprio(0);
    __builtin_amdgcn_sched_barrier(0);
  }

  // epilogue (R6-verified 32x32 C/D map): col=lane&31, row=(reg&3)+8*(reg>>2)+4*(lane>>5)
#pragma unroll
  for (int mf = 0; mf < 4; ++mf)
#pragma unroll
    for (int gq = 0; gq < 4; ++gq) {
      const int o = mbase + wm * 128 + mf * 32 + gq * 8 + khi * 4;
      const float4 bias = *(const float4*)&bconv[o];
#pragma unroll
      for (int nf = 0; nf < 2; ++nf) {
        const int n = wn * 64 + nf * 32 + r32;
        const long p = (long)prow0 + 1 + n;
        union { u16 q[4]; uint2 v; } uo;
        uo.q[0] = f2bf(fmaxf(acc[mf][nf][gq * 4 + 0] + bias.x, 0.f));
        uo.q[1] = f2bf(fmaxf(acc[mf][nf][gq * 4 + 1] + bias.y, 0.f));
        uo.q[2] = f2bf(fmaxf(acc[mf][nf][gq * 4 + 2] + bias.z, 0.f));
        uo.q[3] = f2bf(fmaxf(acc[mf][nf][gq * 4 + 3] + bias.w, 0.f));
        *(uint2*)&hout[p * HID_ + o] = uo.v;
      }
    }
}

// ---------------- proj_out: out[n][j] = h[n][:] @ W_out[:,j] + b_out (fp32 out) ----------------
__global__ __launch_bounds__(256, 2) void proj_out_gemm(const u16* __restrict__ hin,
                                                        const u16* __restrict__ wob,
                                                        const float* __restrict__ bout,
                                                        float* __restrict__ out) {
  __shared__ __align__(16) u16 Ab[2][128 * 32];   // [n][i]
  __shared__ __align__(16) u16 Bb[2][64 * 32];    // [j][i]
  const int tid = threadIdx.x, wid = tid >> 6, lane = tid & 63;
  const int nt = blockIdx.x;
  const int bb = (nt * 128) / S_, s0v = (nt * 128) % S_;
  const int prow0 = bb * SP_ + s0v + 1;
  const int l4 = lane >> 2, lb = (lane & 3) * 8;
  const int fr = lane & 15, fq = lane >> 4;

  f32x4 acc[2][4];
#pragma unroll
  for (int m = 0; m < 2; ++m)
#pragma unroll
    for (int n = 0; n < 4; ++n) acc[m][n] = {0.f, 0.f, 0.f, 0.f};

  auto stage = [&](int buf, int t) {
    const int i0 = t * 32;
#pragma unroll
    for (int c = 0; c < 2; ++c) {
      const int ch = wid * 2 + c;
      gload16(hin + (long)(prow0 + ch * 16 + l4) * HID_ + i0 + lb, &Ab[buf][ch * 512]);
    }
    gload16(wob + (wid * 16 + l4) * HID_ + i0 + lb, &Bb[buf][wid * 512]);
  };

  stage(0, 0);
  __syncthreads();
  for (int t = 0; t < 16; ++t) {
    const int cur = t & 1;
    if (t < 15) stage(cur ^ 1, t + 1);
    bf16x8 af[2], bfv[4];
#pragma unroll
    for (int m = 0; m < 2; ++m)
      af[m] = *(const bf16x8*)&Ab[cur][(wid * 32 + m * 16 + fr) * 32 + fq * 8];
#pragma unroll
    for (int j = 0; j < 4; ++j)
      bfv[j] = *(const bf16x8*)&Bb[cur][(j * 16 + fr) * 32 + fq * 8];
#pragma unroll
    for (int m = 0; m < 2; ++m)
#pragma unroll
      for (int j = 0; j < 4; ++j)
        acc[m][j] = __builtin_amdgcn_mfma_f32_16x16x32_bf16(af[m], bfv[j], acc[m][j], 0, 0, 0);
    __syncthreads();
  }
  const int n0 = nt * 128;
#pragma unroll
  for (int m = 0; m < 2; ++m) {
    const int nbase = n0 + wid * 32 + m * 16 + fq * 4;
#pragma unroll
    for (int jf = 0; jf < 4; ++jf) {
      const int j = jf * 16 + fr;
      const float bj = bout[j];
#pragma unroll
      for (int r = 0; r < 4; ++r)
        out[(long)(nbase + r) * IN_ + j] = acc[m][jf][r] + bj;
    }
  }
}

extern "C" void kernel_launch(void* const* d_in, const int* in_sizes, int n_in,
                              void* d_out, int out_size, void* d_ws, size_t ws_size,
                              hipStream_t stream) {
  (void)in_sizes; (void)n_in; (void)out_size; (void)ws_size;
  const float* x = (const float*)d_in[0];
  const float* W_in = (const float*)d_in[1];
  const float* b_in = (const float*)d_in[2];
  const float* W_conv = (const float*)d_in[3];
  const float* b_conv = (const float*)d_in[4];
  const float* W_out = (const float*)d_in[5];
  const float* b_out = (const float*)d_in[6];
  float* out = (float*)d_out;
  char* ws = (char*)d_ws;

  const size_t hbytes = (size_t)NP_ * HID_ * sizeof(u16);        // 33,570,816 B
  u16* h0 = (u16*)ws;
  u16* h1 = (u16*)(ws + hbytes);
  u16* wcb = (u16*)(ws + 2 * hbytes);
  u16* wib = (u16*)(ws + 2 * hbytes + (size_t)3 * HID_ * HID_ * 2);
  u16* wob = (u16*)(ws + 2 * hbytes + ((size_t)3 * HID_ * HID_ + IN_ * HID_) * 2);
  u16* xbf = (u16*)(ws + 2 * hbytes + ((size_t)3 * HID_ * HID_ + 2 * IN_ * HID_) * 2);

  // allow 128 KiB dynamic LDS for the conv kernel (host-side attr, idempotent)
  static int lds_attr_set = 0;
  if (!lds_attr_set) {
    (void)hipFuncSetAttribute((const void*)conv_gemm11,
                              hipFuncAttributeMaxDynamicSharedMemorySize, 131072);
    lds_attr_set = 1;
  }

  setup_kernel<<<2048, 256, 0, stream>>>(x, W_conv, W_in, W_out, wcb, wib, wob, xbf, h0, h1);
  proj_in_gemm<<<dim3(NTOT / 128, HID_ / 128), 256, 0, stream>>>(xbf, wib, b_in, h0);
  const u16* cin = h0;
  u16* cout = h1;
  for (int s = 0; s < NSTEP; ++s) {
    conv_gemm11<<<256, 512, 131072, stream>>>(cin, cout, wcb, b_conv);
    u16* t = (u16*)cin; cin = cout; cout = t;
  }
  proj_out_gemm<<<NTOT / 128, 256, 0, stream>>>(cin, wob, b_out, out);
}

// Round 12
// 590.746 us; speedup vs baseline: 1.1656x; 1.1656x over previous
//
#include <hip/hip_runtime.h>

#define B_ 8
#define S_ 4096
#define IN_ 64
#define HID_ 512
#define NSTEP 12
#define SP_ (S_ + 2)
#define NP_ (B_ * SP_)
#define NTOT (B_ * S_)

typedef unsigned short u16;
typedef __attribute__((ext_vector_type(8))) short bf16x8;
typedef __attribute__((ext_vector_type(4))) float f32x4;

__device__ __forceinline__ u16 f2bf(float f) {
  unsigned u = __float_as_uint(f);
  u += 0x7fffu + ((u >> 16) & 1u);
  return (u16)(u >> 16);
}

__device__ __forceinline__ void gload16(const void* g, void* l) {
  __builtin_amdgcn_global_load_lds((const __attribute__((address_space(1))) void*)g,
                                   (__attribute__((address_space(3))) void*)l, 16, 0, 0);
}

// ---------------- setup: bf16 conversions + weight transposes + pad-row zeroing ----------------
__global__ void setup_kernel(const float* __restrict__ x, const float* __restrict__ Wc,
                             const float* __restrict__ Wi, const float* __restrict__ Wo,
                             u16* __restrict__ wcb, u16* __restrict__ wib,
                             u16* __restrict__ wob, u16* __restrict__ xbf,
                             u16* __restrict__ h0, u16* __restrict__ h1) {
  const int n_wc = 3 * HID_ * HID_;       // wcb[k][o][i] = Wc[o][i][k]
  const int n_wio = IN_ * HID_;
  const int n_xb = NTOT * IN_;
  const int n_pad = 2 * B_ * 2 * HID_;
  const long total = (long)n_wc + 2 * n_wio + n_xb + n_pad;
  for (long u = (long)blockIdx.x * blockDim.x + threadIdx.x; u < total;
       u += (long)gridDim.x * blockDim.x) {
    long v = u;
    if (v < n_wc) {
      int k = (int)(v / (HID_ * HID_));
      int rem = (int)(v % (HID_ * HID_));
      int o = rem / HID_, i = rem % HID_;
      wcb[v] = f2bf(Wc[((long)o * HID_ + i) * 3 + k]);
    } else if ((v -= n_wc) < n_wio) {      // wib[i][j] = Wi[j][i]
      int i = (int)(v / IN_), j = (int)(v % IN_);
      wib[v] = f2bf(Wi[j * HID_ + i]);
    } else if ((v -= n_wio) < n_wio) {     // wob[j][i] = Wo[i][j]
      int j = (int)(v / HID_), i = (int)(v % HID_);
      wob[v] = f2bf(Wo[i * IN_ + j]);
    } else if ((v -= n_wio) < n_xb) {
      xbf[v] = f2bf(x[v]);
    } else {
      v -= n_xb;                           // zero pad rows (s=-1 and s=S per batch, both buffers)
      int buf = (int)(v / (B_ * 2 * HID_));
      int r = (int)(v % (B_ * 2 * HID_));
      int b = r / (2 * HID_);
      int q = r % (2 * HID_);
      int side = q / HID_, i = q % HID_;
      long p = (long)b * SP_ + (side ? (S_ + 1) : 0);
      (buf ? h1 : h0)[p * HID_ + i] = 0;
    }
  }
}

// ---------------- proj_in: h0[n][i] = x[n][:] @ W_in[:,i] + b_in  (bf16 MFMA, K=64) ----------------
__global__ __launch_bounds__(256, 2) void proj_in_gemm(const u16* __restrict__ xb,
                                                       const u16* __restrict__ wib,
                                                       const float* __restrict__ bin,
                                                       u16* __restrict__ hout) {
  __shared__ __align__(16) u16 Ab[128 * 64];
  __shared__ __align__(16) u16 Bb[128 * 64];
  const int tid = threadIdx.x, wid = tid >> 6, lane = tid & 63;
  const int nt = blockIdx.x, mt = blockIdx.y;
  const int wr = wid >> 1, wcn = wid & 1, fr = lane & 15, fq = lane >> 4;
#pragma unroll
  for (int c = 0; c < 4; ++c) {
    const int ch = wid * 4 + c;
    const int row = ch * 8 + (lane >> 3), cb = (lane & 7) * 8;
    gload16(wib + (mt * 128 + row) * 64 + cb, &Ab[ch * 512]);
    gload16(xb + ((long)nt * 128 + row) * 64 + cb, &Bb[ch * 512]);
  }
  f32x4 acc[4][4];
#pragma unroll
  for (int m = 0; m < 4; ++m)
#pragma unroll
    for (int n = 0; n < 4; ++n) acc[m][n] = {0.f, 0.f, 0.f, 0.f};
  __syncthreads();
#pragma unroll
  for (int t = 0; t < 2; ++t) {
    const int j0 = t * 32;
    bf16x8 af[4], bfv[4];
#pragma unroll
    for (int m = 0; m < 4; ++m)
      af[m] = *(const bf16x8*)&Ab[(wr * 64 + m * 16 + fr) * 64 + j0 + fq * 8];
#pragma unroll
    for (int n = 0; n < 4; ++n)
      bfv[n] = *(const bf16x8*)&Bb[(wcn * 64 + n * 16 + fr) * 64 + j0 + fq * 8];
#pragma unroll
    for (int m = 0; m < 4; ++m)
#pragma unroll
      for (int n = 0; n < 4; ++n)
        acc[m][n] = __builtin_amdgcn_mfma_f32_16x16x32_bf16(af[m], bfv[n], acc[m][n], 0, 0, 0);
  }
  const int n0 = nt * 128;
  const int bb = n0 / S_, s0v = n0 % S_;
  const int prow = bb * SP_ + s0v + 1;
#pragma unroll
  for (int m = 0; m < 4; ++m) {
    const int i = mt * 128 + wr * 64 + m * 16 + fq * 4;
    const float4 bias = *(const float4*)&bin[i];
#pragma unroll
    for (int n = 0; n < 4; ++n) {
      const int nl = wcn * 64 + n * 16 + fr;
      const long p = prow + nl;
      union { u16 q[4]; uint2 v; } u;
      u.q[0] = f2bf(acc[m][n][0] + bias.x);
      u.q[1] = f2bf(acc[m][n][1] + bias.y);
      u.q[2] = f2bf(acc[m][n][2] + bias.z);
      u.q[3] = f2bf(acc[m][n][3] + bias.w);
      *(uint2*)&hout[p * HID_ + i] = u.v;
    }
  }
}

// ---------------- conv step: 256x256 tile, BK=32, 4 LDS buffers, depth-3 prefetch ----------------
// C[o,n] = relu(sum_{k,i} W[o,i,k] h[i,n+k-1] + b), bf16 in/out.  [R3 — measured optimum]
// LDS: 4 bufs x (A 256x32 + B 256x32) bf16 = 128 KiB. Rows are 64 B; swizzle
// byte ^= ((row>>1)&3)<<4 (involution; 0 bank conflicts measured).
// Schedule per K-tile: vmcnt(8), barrier, {reads g1 | stage t+3 | reads g2},
// lgkmcnt(4) -> 16 MFMA, lgkmcnt(0) -> 16 MFMA. One barrier/tile, never vmcnt(0).
// Measured: 51.7-52.7 us/step, MfmaUtil ~40%, 0 conflicts, FETCH 22.8 MB.
// Variants R4-R11 (8-phase, 32x32, frag-major, A-from-L2, 2-block dephase) all lost.
__global__ __launch_bounds__(512, 2) void conv_gemm3(const u16* __restrict__ hin,
                                                     u16* __restrict__ hout,
                                                     const u16* __restrict__ wcb,
                                                     const float* __restrict__ bconv) {
  extern __shared__ __align__(16) u16 smem[];
  const int tid = threadIdx.x;
  const int w = tid >> 6, lane = tid & 63;
  const int wm = w >> 2, wn = w & 3;          // 2 x 4 wave grid; per-wave C = 128 x 64
  const int fr = lane & 15, fq = lane >> 4;
  const int mbase = blockIdx.y * 256;
  const int n0 = blockIdx.x * 256;
  const int bb = n0 / S_, s0 = n0 % S_;
  const int prow0 = bb * SP_ + s0;            // tap-k B rows start at prow0+k

  // staging geometry: linear LDS byte d = c*8192 + tid*16; logical byte
  // l = d ^ (((d>>7)&3)<<4) -> pre-swizzled global source (m173 pattern).
  const int tl = (tid * 16) ^ (((tid >> 3) & 3) << 4);
  const int srow = tl >> 6;                   // 0..127 (chunk-local row)
  const int scol = (tl & 63) >> 1;            // element col (multiple of 8)
  const int wdst = w * 1024;                  // wave-uniform LDS byte base within chunk

  auto stage = [&](int dbuf, int u) {
    const int kk = u % 3;                     // tap (tap-inner: L2-hot re-reads)
    const int i0 = (u / 3) * 32;              // input-channel slice
    char* base = (char*)smem + (size_t)dbuf * 32768;
    const u16* ga = wcb + (size_t)kk * (HID_ * HID_) + (size_t)(mbase + srow) * HID_ + i0 + scol;
    const u16* gb = hin + (size_t)(prow0 + kk + srow) * HID_ + i0 + scol;
    gload16(ga, base + wdst);
    gload16(ga + 128 * HID_, base + 8192 + wdst);
    gload16(gb, base + 16384 + wdst);
    gload16(gb + 128 * HID_, base + 24576 + wdst);
  };

  f32x4 acc[8][4];
#pragma unroll
  for (int m = 0; m < 8; ++m)
#pragma unroll
    for (int n = 0; n < 4; ++n) acc[m][n] = {0.f, 0.f, 0.f, 0.f};

  stage(0, 0);
  stage(1, 1);
  stage(2, 2);

  // ds_read offsets: byte = row*64 + fq*16, swizzle XOR = ((fr>>1)&3)<<4
  // (wm*128, wn*64, m*16, n*16 are all ==0 mod 8 rows -> swz depends on fr only).
  const int swzb = ((fr >> 1) & 3) << 4;
  const int aoffs = (((wm * 128 + fr) * 64 + fq * 16)) ^ swzb;
  const int boffs = (((wn * 64 + fr) * 64 + fq * 16)) ^ swzb;

#pragma unroll 12
  for (int t = 0; t < 48; ++t) {
    const int buf = t & 3;
    const char* A = (const char*)smem + (size_t)buf * 32768;
    const char* Bv = A + 16384;

    // this wave's tile-t loads done (<=8 outstanding); barrier proves ALL waves' are
    asm volatile("s_waitcnt vmcnt(8)" ::: "memory");
    __builtin_amdgcn_sched_barrier(0);
    __builtin_amdgcn_s_barrier();
    __builtin_amdgcn_sched_barrier(0);

    bf16x8 af[8], bfv[4];
    // group 1: A m0-3 + B n0-3 (8 ds_reads)
#pragma unroll
    for (int m = 0; m < 4; ++m)
      af[m] = *(const bf16x8*)(A + aoffs + m * 1024);
#pragma unroll
    for (int n = 0; n < 4; ++n)
      bfv[n] = *(const bf16x8*)(Bv + boffs + n * 1024);
    __builtin_amdgcn_sched_barrier(0);
    // prefetch K-tile t+3 (depth 3 ~= 3 tiles issue-to-wait; dummy re-stage past end)
    {
      int u = t + 3;
      if (u > 47) u = 47;
      stage((t + 3) & 3, u);
    }
    __builtin_amdgcn_sched_barrier(0);
    // group 2: A m4-7 (4 ds_reads)
#pragma unroll
    for (int m = 4; m < 8; ++m)
      af[m] = *(const bf16x8*)(A + aoffs + m * 1024);
    __builtin_amdgcn_sched_barrier(0);

    // phase 0: group-1 frags ready (group 2 may still fly)
    asm volatile("s_waitcnt lgkmcnt(4)" ::: "memory");
    __builtin_amdgcn_sched_barrier(0);
    __builtin_amdgcn_s_setprio(1);
#pragma unroll
    for (int m = 0; m < 4; ++m)
#pragma unroll
      for (int n = 0; n < 4; ++n)
        acc[m][n] = __builtin_amdgcn_mfma_f32_16x16x32_bf16(af[m], bfv[n], acc[m][n], 0, 0, 0);
    __builtin_amdgcn_s_setprio(0);
    __builtin_amdgcn_sched_barrier(0);

    // phase 1: rest of A
    asm volatile("s_waitcnt lgkmcnt(0)" ::: "memory");
    __builtin_amdgcn_sched_barrier(0);
    __builtin_amdgcn_s_setprio(1);
#pragma unroll
    for (int m = 4; m < 8; ++m)
#pragma unroll
      for (int n = 0; n < 4; ++n)
        acc[m][n] = __builtin_amdgcn_mfma_f32_16x16x32_bf16(af[m], bfv[n], acc[m][n], 0, 0, 0);
    __builtin_amdgcn_s_setprio(0);
    __builtin_amdgcn_sched_barrier(0);
  }

  // epilogue: bias + relu + bf16 store (4 consecutive channels per 8B store)
#pragma unroll
  for (int m = 0; m < 8; ++m) {
    const int o = mbase + wm * 128 + m * 16 + fq * 4;
    const float4 bias = *(const float4*)&bconv[o];
#pragma unroll
    for (int n = 0; n < 4; ++n) {
      const int nl = wn * 64 + n * 16 + fr;
      const long p = (long)prow0 + 1 + nl;
      union { u16 q[4]; uint2 v; } u;
      u.q[0] = f2bf(fmaxf(acc[m][n][0] + bias.x, 0.f));
      u.q[1] = f2bf(fmaxf(acc[m][n][1] + bias.y, 0.f));
      u.q[2] = f2bf(fmaxf(acc[m][n][2] + bias.z, 0.f));
      u.q[3] = f2bf(fmaxf(acc[m][n][3] + bias.w, 0.f));
      *(uint2*)&hout[p * HID_ + o] = u.v;
    }
  }
}

// ---------------- proj_out: out[n][j] = h[n][:] @ W_out[:,j] + b_out (fp32 out) ----------------
__global__ __launch_bounds__(256, 2) void proj_out_gemm(const u16* __restrict__ hin,
                                                        const u16* __restrict__ wob,
                                                        const float* __restrict__ bout,
                                                        float* __restrict__ out) {
  __shared__ __align__(16) u16 Ab[2][128 * 32];   // [n][i]
  __shared__ __align__(16) u16 Bb[2][64 * 32];    // [j][i]
  const int tid = threadIdx.x, wid = tid >> 6, lane = tid & 63;
  const int nt = blockIdx.x;
  const int bb = (nt * 128) / S_, s0v = (nt * 128) % S_;
  const int prow0 = bb * SP_ + s0v + 1;
  const int l4 = lane >> 2, lb = (lane & 3) * 8;
  const int fr = lane & 15, fq = lane >> 4;

  f32x4 acc[2][4];
#pragma unroll
  for (int m = 0; m < 2; ++m)
#pragma unroll
    for (int n = 0; n < 4; ++n) acc[m][n] = {0.f, 0.f, 0.f, 0.f};

  auto stage = [&](int buf, int t) {
    const int i0 = t * 32;
#pragma unroll
    for (int c = 0; c < 2; ++c) {
      const int ch = wid * 2 + c;
      gload16(hin + (long)(prow0 + ch * 16 + l4) * HID_ + i0 + lb, &Ab[buf][ch * 512]);
    }
    gload16(wob + (wid * 16 + l4) * HID_ + i0 + lb, &Bb[buf][wid * 512]);
  };

  stage(0, 0);
  __syncthreads();
  for (int t = 0; t < 16; ++t) {
    const int cur = t & 1;
    if (t < 15) stage(cur ^ 1, t + 1);
    bf16x8 af[2], bfv[4];
#pragma unroll
    for (int m = 0; m < 2; ++m)
      af[m] = *(const bf16x8*)&Ab[cur][(wid * 32 + m * 16 + fr) * 32 + fq * 8];
#pragma unroll
    for (int j = 0; j < 4; ++j)
      bfv[j] = *(const bf16x8*)&Bb[cur][(j * 16 + fr) * 32 + fq * 8];
#pragma unroll
    for (int m = 0; m < 2; ++m)
#pragma unroll
      for (int j = 0; j < 4; ++j)
        acc[m][j] = __builtin_amdgcn_mfma_f32_16x16x32_bf16(af[m], bfv[j], acc[m][j], 0, 0, 0);
    __syncthreads();
  }
  const int n0 = nt * 128;
#pragma unroll
  for (int m = 0; m < 2; ++m) {
    const int nbase = n0 + wid * 32 + m * 16 + fq * 4;
#pragma unroll
    for (int jf = 0; jf < 4; ++jf) {
      const int j = jf * 16 + fr;
      const float bj = bout[j];
#pragma unroll
      for (int r = 0; r < 4; ++r)
        out[(long)(nbase + r) * IN_ + j] = acc[m][jf][r] + bj;
    }
  }
}

extern "C" void kernel_launch(void* const* d_in, const int* in_sizes, int n_in,
                              void* d_out, int out_size, void* d_ws, size_t ws_size,
                              hipStream_t stream) {
  (void)in_sizes; (void)n_in; (void)out_size; (void)ws_size;
  const float* x = (const float*)d_in[0];
  const float* W_in = (const float*)d_in[1];
  const float* b_in = (const float*)d_in[2];
  const float* W_conv = (const float*)d_in[3];
  const float* b_conv = (const float*)d_in[4];
  const float* W_out = (const float*)d_in[5];
  const float* b_out = (const float*)d_in[6];
  float* out = (float*)d_out;
  char* ws = (char*)d_ws;

  const size_t hbytes = (size_t)NP_ * HID_ * sizeof(u16);        // 33,570,816 B
  u16* h0 = (u16*)ws;
  u16* h1 = (u16*)(ws + hbytes);
  u16* wcb = (u16*)(ws + 2 * hbytes);
  u16* wib = (u16*)(ws + 2 * hbytes + (size_t)3 * HID_ * HID_ * 2);
  u16* wob = (u16*)(ws + 2 * hbytes + ((size_t)3 * HID_ * HID_ + IN_ * HID_) * 2);
  u16* xbf = (u16*)(ws + 2 * hbytes + ((size_t)3 * HID_ * HID_ + 2 * IN_ * HID_) * 2);

  // allow 128 KiB dynamic LDS for the conv kernel (host-side attr, idempotent)
  static int lds_attr_set = 0;
  if (!lds_attr_set) {
    (void)hipFuncSetAttribute((const void*)conv_gemm3,
                              hipFuncAttributeMaxDynamicSharedMemorySize, 131072);
    lds_attr_set = 1;
  }

  setup_kernel<<<2048, 256, 0, stream>>>(x, W_conv, W_in, W_out, wcb, wib, wob, xbf, h0, h1);
  proj_in_gemm<<<dim3(NTOT / 128, HID_ / 128), 256, 0, stream>>>(xbf, wib, b_in, h0);
  const u16* cin = h0;
  u16* cout = h1;
  for (int s = 0; s < NSTEP; ++s) {
    conv_gemm3<<<dim3(NTOT / 256, 2), 512, 131072, stream>>>(cin, cout, wcb, b_conv);
    u16* t = (u16*)cin; cin = cout; cout = t;
  }
  proj_out_gemm<<<NTOT / 128, 256, 0, stream>>>(cin, wob, b_out, out);
}